// Round 1
// 263.731 us; speedup vs baseline: 1.0065x; 1.0065x over previous
//
#include <hip/hip_runtime.h>

// Problem constants
#define V_CNT   10475
#define M_A     704
#define N_A     128
#define KB      10
#define D_TOT   270336       // 704*128*3
#define ROW384  384          // 128*3 floats per m-row of a pc row
#define NCHUNK  44           // 704 / MT
#define MT      16           // m-tile in pcpass
#define LSTR    388          // LDS row stride: 388%32=4 breaks bank conflicts, %4==0 keeps float4 alignment

// ws layout (float offsets) -- NO global atomics anywhere, so NO memset needed.
#define WS_JJP    0          // 28*33 = 924   JJpart[blk][33]
#define WS_JJ     960        // 33            (k_red2 blk 128)
#define WS_MCP    1024       // 88*384        Mcpart[blk][384]
#define WS_MC     34816      // 384           (k_red2 blk 128)
#define WS_CMP    35200      // 44*128        cmpart[chunk][pid]
#define WS_SAP    41344      // 64*4*3        sapart[b][slice][3]
#define WS_GWS    42112      // 64*128        FINAL gamma (k_red2)
#define WS_X      50304      // 64*2496       X[b][e]: [obj(384); sa0(2112)]
#define WS_WP     210048     // 128*2496      Wp[p][e]: [0,384)=U (k_red2), [384,2496)=-V2 (k_main)
#define WS_UPART  529536     // 44*128*384    Upart[chunk][pid][nc]
#define WS_TOTAL  2692224    // floats (10.8 MB)

#define NJ_BLK 28
#define NM_BLK 88
#define NP_BLK 256           // 64 b * 4 slices
#define NPC    (NCHUNK * 128)  // 5632 pcpass blocks

// ---------------------------------------------------------------- K1: pcpass + all precompute fused
// blocks [0,5632): single pass over pca_components (16x384 tile of pc row pid):
//   Upart[chunk][pid][0:384] = column sums over 16 m's
//   Wp[pid][384+m0*3 : +48]  = -(row sums over n)
//   cmpart[chunk][pid]       = tile . mean-tile
// blocks [5632,+28): J-reduce partials; [+28,+116): Mc partials; [+116,+372): per-b prep
__global__ __launch_bounds__(384) void k_main(
    const float* __restrict__ pc, const float* __restrict__ mean,
    const float* __restrict__ Jr, const float* __restrict__ vt,
    const float* __restrict__ sd, const float* __restrict__ betas,
    const float* __restrict__ rot, const float* __restrict__ trans,
    const float* __restrict__ org, const int* __restrict__ anch,
    float* __restrict__ Upart, float* __restrict__ Wp,
    float* __restrict__ cmpart, float* __restrict__ JJpart,
    float* __restrict__ Mcpart, float* __restrict__ X,
    float* __restrict__ sapart) {
  __shared__ float tile[MT * LSTR];  // 24,832 B; pre-branches alias into it
  __shared__ float red[384];
  __shared__ float cred[6];
  __shared__ float jjs[33];          // separate so LDS atomics are unambiguous
  const int blk = blockIdx.x, t = threadIdx.x;

  if (blk < NPC) {
    // ---------------- pcpass (BW-critical; launched first so it owns the machine)
    const int pid = blk & 127;
    const int chunk = blk >> 7;  // 0..43
    const int m0 = chunk * MT;
    const float* row = pc + (size_t)pid * D_TOT + (size_t)m0 * ROW384;
    const float* mrow = mean + (size_t)m0 * ROW384;

    float cm = 0.f;
#pragma unroll
    for (int i = 0; i < 4; ++i) {
      int f = 1536 * i + 4 * t;
      float4 pv = *(const float4*)(row + f);
      float4 mv = *(const float4*)(mrow + f);
      cm += pv.x * mv.x + pv.y * mv.y + pv.z * mv.z + pv.w * mv.w;
      int m_l = 4 * i + t / 96;
      int col = (t % 96) * 4;
      *(float4*)(&tile[m_l * LSTR + col]) = pv;
    }
    __syncthreads();  // S1

    {  // U partial: fixed (n,c)=t, sum over 16 m -> contiguous store
      float u = 0.f;
#pragma unroll
      for (int m = 0; m < MT; ++m) u += tile[m * LSTR + t];
      Upart[((size_t)chunk * 128 + pid) * 384 + t] = u;
    }
    {  // V partial: t = grp*48 + (m_l*3+c), grp 0..7 each sums 16 n's
      int grp = t / 48, mc = t % 48, m_l = mc / 3, c = mc % 3;
      const float* tp = &tile[m_l * LSTR + c];
      float vsp = 0.f;
#pragma unroll 8
      for (int j = 0; j < 16; ++j) vsp += tp[(grp * 16 + j) * 3];
      red[t] = vsp;
    }
    {  // cmean wave-reduce
      float x = cm;
      for (int off = 32; off > 0; off >>= 1) x += __shfl_down(x, off);
      if ((t & 63) == 0) cred[t >> 6] = x;
    }
    __syncthreads();  // S2
    if (t < 48) {
      float vs = 0.f;
#pragma unroll
      for (int g = 0; g < 8; ++g) vs += red[g * 48 + t];
      Wp[(size_t)pid * 2496 + 384 + m0 * 3 + t] = -vs;  // -V2; contiguous, exclusive
    }
    if (t == 0)
      cmpart[chunk * 128 + pid] =
          cred[0] + cred[1] + cred[2] + cred[3] + cred[4] + cred[5];
    return;
  }

  const int pblk = blk - NPC;
  float* orgL = tile;          // 384
  float* smallv = tile + 384;  // 24: 0..9 betas, 10..18 rot, 19..21 trans

  if (pblk < NJ_BLK) {
    // ---------------- J-regressor partials (register-light: one jr*x at a time)
    if (t < 33) jjs[t] = 0.f;
    __syncthreads();
    const int v = pblk * 384 + t;
    const bool ok = v < V_CNT;
    const float jr = ok ? Jr[v] : 0.f;
    const float* vp = vt + (size_t)v * 3;
    const float* sp = sd + (size_t)v * 30;
#pragma unroll 1
    for (int i = 0; i < 33; ++i) {
      float x = 0.f;
      if (ok) x = (i < 3) ? vp[i] : sp[i - 3];
      float val = jr * x;
#pragma unroll
      for (int off = 32; off > 0; off >>= 1) val += __shfl_down(val, off);
      if ((t & 63) == 0) atomicAdd(&jjs[i], val);  // LDS atomic
    }
    __syncthreads();
    if (t < 33) JJpart[pblk * 33 + t] = jjs[t];
  } else if (pblk < NJ_BLK + NM_BLK) {
    // ---------------- Mc partials
    int j = pblk - NJ_BLK;
    float a = 0.f;
#pragma unroll
    for (int mi = 0; mi < 8; ++mi)
      a += mean[(size_t)(j * 8 + mi) * ROW384 + t];
    Mcpart[(size_t)j * 384 + t] = a;
  } else {
    // ---------------- per-batch prep: b = idx/4; slice sl owns sa [sl*528, +528)
    const int idx = pblk - (NJ_BLK + NM_BLK);
    const int b = idx >> 2, sl = idx & 3;
    if (t < 10) smallv[t] = betas[b * 10 + t];
    else if (t < 19) smallv[t] = rot[b * 9 + (t - 10)];
    else if (t < 22) smallv[t] = trans[b * 3 + (t - 19)];
    if (sl == 0) orgL[t] = org[(size_t)b * 384 + t];
    __syncthreads();
    if (sl == 0) {
      int n = t / 3, d = t % 3;
      X[(size_t)b * 2496 + t] =
          orgL[n * 3 + 0] * smallv[10 + d * 3 + 0] +
          orgL[n * 3 + 1] * smallv[10 + d * 3 + 1] +
          orgL[n * 3 + 2] * smallv[10 + d * 3 + 2] + smallv[19 + d];
    }
    float ps = 0.f;
#pragma unroll
    for (int r = 0; r < 2; ++r) {
      int el = t + r * 384;
      if (el < 528) {
        int e = sl * 528 + el;
        int m = e / 3, c = e - m * 3;
        int a = anch[m];
        const float* sp = sd + ((size_t)a * 3 + c) * KB;
        float val = vt[a * 3 + c];
#pragma unroll
        for (int k = 0; k < KB; ++k) val += smallv[k] * sp[k];
        X[(size_t)b * 2496 + 384 + e] = val;
        ps += val;
      }
    }
    red[t] = ps;
    __syncthreads();
    if (t < 3) {
      float s = 0.f;
#pragma unroll 8
      for (int j = 0; j < 128; ++j) s += red[t + 3 * j];
      sapart[idx * 3 + t] = s;
    }
  }
}

// ---------------------------------------------------------------- K2: reductions + FULL gamma
// blocks [0,128): pid-blocks -- finish W row, then compute FINAL gamma[b][pid] for all 64 b
//                 (each block already holds its entire W row: no separate k_gamma pass)
// block 128: JJ + Mc reductions
__global__ __launch_bounds__(384) void k_red2(
    const float* __restrict__ Upart, const float* __restrict__ JJpart,
    const float* __restrict__ Mcpart, const float* __restrict__ cmpart,
    const float* __restrict__ betas, const float* __restrict__ X,
    float* __restrict__ Wp, float* __restrict__ JJ, float* __restrict__ Mc,
    float* __restrict__ gWS, float* __restrict__ out) {
  const int t = threadIdx.x;
  if (blockIdx.x == 128) {
    if (t < 33) {
      float s = 0.f;
#pragma unroll 4
      for (int j = 0; j < NJ_BLK; ++j) s += JJpart[j * 33 + t];
      JJ[t] = s;
    }
    float s = 0.f;
#pragma unroll 4
    for (int j = 0; j < NM_BLK; ++j) s += Mcpart[(size_t)j * 384 + t];
    Mc[t] = s;
    return;
  }
  __shared__ __align__(16) float Wl[2496];  // full W row for this pid
  __shared__ float red[384];
  __shared__ float J0s[192];  // J0[b][c] for all 64 b
  __shared__ float jjl[33];
  __shared__ float cmv[4];    // [0..2]=V2c components, [3]=cmean
  const int pid = blockIdx.x;

  // U row: reduce Upart chunks; keep in LDS and publish to Wp (k_finish A-loop needs it)
  {
    float u = 0.f;
#pragma unroll 4
    for (int c = 0; c < NCHUNK; ++c)
      u += Upart[((size_t)c * 128 + pid) * 384 + t];
    Wp[(size_t)pid * 2496 + t] = u;
    Wl[t] = u;
  }
  // -V2 region (written by k_main) -> LDS; accumulate for V2c
  {
    float s = 0.f;
    const float* vr = Wp + (size_t)pid * 2496 + 384;
#pragma unroll
    for (int j = 0; j < 6; ++j) {
      int idx = t + 384 * j;
      if (idx < 2112) {
        float v = vr[idx];
        Wl[384 + idx] = v;
        s += v;
      }
    }
    red[t] = s;
  }
  // JJ local reduce (cheap: 28x33)
  if (t < 33) {
    float a = 0.f;
#pragma unroll 4
    for (int j = 0; j < NJ_BLK; ++j) a += JJpart[j * 33 + t];
    jjl[t] = a;
  }
  // cmean[pid] = sum_chunk cmpart (wave 0)
  if (t < 64) {
    float x = (t < NCHUNK) ? cmpart[t * 128 + pid] : 0.f;
#pragma unroll
    for (int off = 32; off > 0; off >>= 1) x += __shfl_down(x, off);
    if (t == 0) cmv[3] = x;
  }
  __syncthreads();
  if (t < 3) {  // V2c_c = -(sum of the -V2 values); thread t covers c = t%3 lanes
    float acc = 0.f;
#pragma unroll 8
    for (int j = 0; j < 128; ++j) acc += red[t + 3 * j];
    cmv[t] = -acc;
  }
  if (t < 192) {  // J0[b][c] for all b
    int b = t / 3, c = t - 3 * (t / 3);
    float j0 = jjl[c];
#pragma unroll
    for (int k = 0; k < KB; ++k) j0 += betas[b * 10 + k] * jjl[3 + c * 10 + k];
    J0s[t] = j0;
  }
  __syncthreads();

  // gamma: wave w handles b = w, w+6, ... ; dot(X[b], Wl) + J0.V2c - cmean
  const int w = t >> 6, l = t & 63;
  const float4* W4 = (const float4*)Wl;
  for (int b = w; b < 64; b += 6) {
    const float4* X4 = (const float4*)(X + (size_t)b * 2496);
    float dot = 0.f;
#pragma unroll
    for (int i = 0; i < 10; ++i) {
      int idx = i * 64 + l;
      if (idx < 624) {  // 2496/4
        float4 xv = X4[idx];
        float4 wv = W4[idx];
        dot += xv.x * wv.x + xv.y * wv.y + xv.z * wv.z + xv.w * wv.w;
      }
    }
#pragma unroll
    for (int off = 32; off > 0; off >>= 1) dot += __shfl_down(dot, off);
    if (l == 0) {
      float g = dot + J0s[b * 3 + 0] * cmv[0] + J0s[b * 3 + 1] * cmv[1] +
                J0s[b * 3 + 2] * cmv[2] - cmv[3];
      gWS[b * 128 + pid] = g;
      out[b * 128 + pid] = g;  // output 0 (final)
    }
  }
}

// ---------------------------------------------------------------- 3x3 SVD -> rotation (Kabsch w/ reflection fix)
__device__ inline double det3(const double A[3][3]) {
  return A[0][0] * (A[1][1] * A[2][2] - A[1][2] * A[2][1])
       - A[0][1] * (A[1][0] * A[2][2] - A[1][2] * A[2][0])
       + A[0][2] * (A[1][0] * A[2][1] - A[1][1] * A[2][0]);
}

__device__ void svd3_rotation(const float* S, float* Rout) {
  double M[3][3], B[3][3], Vv[3][3];
  for (int i = 0; i < 3; ++i)
    for (int j = 0; j < 3; ++j) M[i][j] = (double)S[i * 3 + j];
  for (int i = 0; i < 3; ++i)
    for (int j = 0; j < 3; ++j) {
      double a = 0;
      for (int k = 0; k < 3; ++k) a += M[k][i] * M[k][j];
      B[i][j] = a;
    }
  for (int i = 0; i < 3; ++i)
    for (int j = 0; j < 3; ++j) Vv[i][j] = (i == j) ? 1.0 : 0.0;
  const int PP[3] = {0, 0, 1}, QQ[3] = {1, 2, 2};
  for (int sweep = 0; sweep < 25; ++sweep) {
    double off = B[0][1] * B[0][1] + B[0][2] * B[0][2] + B[1][2] * B[1][2];
    double dg = B[0][0] * B[0][0] + B[1][1] * B[1][1] + B[2][2] * B[2][2];
    if (off <= 1e-28 * (dg + 1e-300)) break;
    for (int pr = 0; pr < 3; ++pr) {
      int p = PP[pr], q = QQ[pr];
      double apq = B[p][q];
      if (apq == 0.0) continue;
      double dd = (B[p][p] - B[q][q]) / (2.0 * apq);
      double tt = 1.0 / (fabs(dd) + sqrt(dd * dd + 1.0));
      if (dd < 0.0) tt = -tt;
      double cc = 1.0 / sqrt(tt * tt + 1.0), ss = tt * cc;
      B[p][p] += tt * apq;
      B[q][q] -= tt * apq;
      B[p][q] = B[q][p] = 0.0;
      int k = 3 - p - q;
      double Bkp = cc * B[k][p] + ss * B[k][q];
      double Bkq = -ss * B[k][p] + cc * B[k][q];
      B[k][p] = B[p][k] = Bkp;
      B[k][q] = B[q][k] = Bkq;
      for (int i = 0; i < 3; ++i) {
        double vip = cc * Vv[i][p] + ss * Vv[i][q];
        double viq = -ss * Vv[i][p] + cc * Vv[i][q];
        Vv[i][p] = vip;
        Vv[i][q] = viq;
      }
    }
  }
  double lam[3] = {B[0][0], B[1][1], B[2][2]};
  int o0 = 0, o1 = 1, o2 = 2, tp;
  if (lam[o0] < lam[o1]) { tp = o0; o0 = o1; o1 = tp; }
  if (lam[o0] < lam[o2]) { tp = o0; o0 = o2; o2 = tp; }
  if (lam[o1] < lam[o2]) { tp = o1; o1 = o2; o2 = tp; }
  int ord[3] = {o0, o1, o2};
  double sv[3], U[3][3], Vs[3][3];
  for (int j = 0; j < 3; ++j) {
    double l = lam[ord[j]];
    sv[j] = l > 0.0 ? sqrt(l) : 0.0;
    for (int i = 0; i < 3; ++i) Vs[i][j] = Vv[i][ord[j]];
  }
  for (int j = 0; j < 3; ++j) {
    double vx = Vs[0][j], vy = Vs[1][j], vz = Vs[2][j];
    double ux = M[0][0] * vx + M[0][1] * vy + M[0][2] * vz;
    double uy = M[1][0] * vx + M[1][1] * vy + M[1][2] * vz;
    double uz = M[2][0] * vx + M[2][1] * vy + M[2][2] * vz;
    double sj = sv[j];
    if (sj > 1e-12 * (sv[0] + 1e-300)) {
      U[0][j] = ux / sj; U[1][j] = uy / sj; U[2][j] = uz / sj;
    } else if (j == 2) {
      double cx = U[1][0] * U[2][1] - U[2][0] * U[1][1];
      double cy = U[2][0] * U[0][1] - U[0][0] * U[2][1];
      double cz = U[0][0] * U[1][1] - U[1][0] * U[0][1];
      double nn = sqrt(cx * cx + cy * cy + cz * cz);
      if (nn < 1e-300) { cx = 0; cy = 0; cz = 1; nn = 1; }
      U[0][2] = cx / nn; U[1][2] = cy / nn; U[2][2] = cz / nn;
    } else {
      U[0][j] = (j == 0) ? 1.0 : 0.0;
      U[1][j] = (j == 1) ? 1.0 : 0.0;
      U[2][j] = 0.0;
    }
  }
  double dsgn = (det3(U) * det3(Vs)) < 0.0 ? -1.0 : 1.0;
  for (int i = 0; i < 3; ++i)
    for (int j = 0; j < 3; ++j)
      Rout[i * 3 + j] = (float)(U[i][0] * Vs[j][0] + U[i][1] * Vs[j][1] +
                                dsgn * U[i][2] * Vs[j][2]);
}

// ---------------------------------------------------------------- K3: finalize per batch (gamma already done)
__global__ __launch_bounds__(384) void k_finish(
    const float* __restrict__ betas, const float* __restrict__ org,
    const float* __restrict__ JJ, const float* __restrict__ Mc,
    const float* __restrict__ sapart, const float* __restrict__ gWS,
    const float* __restrict__ Wp, float* __restrict__ out) {
  const int b = blockIdx.x, t = threadIdx.x;
  __shared__ float orgL[384];
  __shared__ __align__(16) float A[384];
  __shared__ float4 redA[4][96];  // A partials: 4 p-groups
  __shared__ float gammaL[128];
  __shared__ float betasL[10], J0L[3], cQ[3], smat[9], RL[9];

  if (t < 10) betasL[t] = betas[b * 10 + t];
  orgL[t] = org[(size_t)b * 384 + t];
  if (t >= 256) gammaL[t - 256] = gWS[b * 128 + (t - 256)];  // final gamma
  __syncthreads();
  if (t < 3) {
    float j0 = JJ[t];
#pragma unroll
    for (int k = 0; k < KB; ++k) j0 += betasL[k] * JJ[3 + t * KB + k];
    J0L[t] = j0;
    float s = 0.f;
    for (int n = 0; n < N_A; ++n) s += orgL[n * 3 + t];
    cQ[t] = s * (1.f / 128.f);
  }

  // A[nc] = Mc + sum_p gamma[p]*Wp[p][nc] -- all 384 threads: grp owns 32 p's
  {
    int grp = t / 96, tn = t - grp * 96;
    float4 gs = {0.f, 0.f, 0.f, 0.f};
#pragma unroll 8
    for (int i = 0; i < 32; ++i) {
      int p = grp * 32 + i;
      float4 wv = *(const float4*)(Wp + (size_t)p * 2496 + 4 * tn);
      float g = gammaL[p];
      gs.x += g * wv.x; gs.y += g * wv.y; gs.z += g * wv.z; gs.w += g * wv.w;
    }
    redA[grp][tn] = gs;
  }
  __syncthreads();
  if (t < 96) {
    float4 s0 = redA[0][t], s1 = redA[1][t], s2 = redA[2][t], s3 = redA[3][t];
    float4 m4 = *(const float4*)(Mc + 4 * t);
    float4 a4 = {m4.x + s0.x + s1.x + s2.x + s3.x,
                 m4.y + s0.y + s1.y + s2.y + s3.y,
                 m4.z + s0.z + s1.z + s2.z + s3.z,
                 m4.w + s0.w + s1.w + s2.w + s3.w};
    *(float4*)(&A[4 * t]) = a4;
  }
  __syncthreads();

  if (t < 9) {
    int c = t / 3, d = t % 3;
    float s = 0.f, cq = cQ[d];
    for (int n = 0; n < N_A; ++n) s += A[n * 3 + c] * (orgL[n * 3 + d] - cq);
    smat[t] = s;
  }
  __syncthreads();
  if (t == 0) svd3_rotation(smat, RL);
  __syncthreads();
  if (t < 9) out[8192 + b * 9 + t] = RL[t];  // output 1
  if (t < 3) {
    float sSum = sapart[(b * 4 + 0) * 3 + t] + sapart[(b * 4 + 1) * 3 + t] +
                 sapart[(b * 4 + 2) * 3 + t] + sapart[(b * 4 + 3) * 3 + t];
    float s2 = 0.f;
    for (int n = 0; n < N_A; ++n) s2 += A[n * 3 + t];
    float meanP = sSum * (1.f / 704.f) - J0L[t] + s2 * (1.f / 90112.f);
    float rq = RL[t * 3 + 0] * cQ[0] + RL[t * 3 + 1] * cQ[1] + RL[t * 3 + 2] * cQ[2];
    out[8768 + b * 3 + t] = meanP - rq;  // output 2
  }
}

// ----------------------------------------------------------------
extern "C" void kernel_launch(void* const* d_in, const int* in_sizes, int n_in,
                              void* d_out, int out_size, void* d_ws, size_t ws_size,
                              hipStream_t stream) {
  const float* betas = (const float*)d_in[0];
  const float* rot   = (const float*)d_in[1];
  const float* trans = (const float*)d_in[2];
  const float* org   = (const float*)d_in[3];
  const float* vt    = (const float*)d_in[4];
  const float* sd    = (const float*)d_in[5];
  const float* Jr    = (const float*)d_in[6];
  const float* mean  = (const float*)d_in[7];
  const float* pc    = (const float*)d_in[8];
  const int*   anch  = (const int*)d_in[9];
  float* out = (float*)d_out;
  float* ws  = (float*)d_ws;
  if (ws_size < (size_t)WS_TOTAL * sizeof(float)) return;  // need ~10.8 MB scratch

  float* JJpart = ws + WS_JJP;
  float* JJ     = ws + WS_JJ;
  float* Mcpart = ws + WS_MCP;
  float* Mc     = ws + WS_MC;
  float* cmpart = ws + WS_CMP;
  float* sapart = ws + WS_SAP;
  float* gWS    = ws + WS_GWS;
  float* X      = ws + WS_X;
  float* Wp     = ws + WS_WP;
  float* Upart  = ws + WS_UPART;

  k_main<<<NPC + NJ_BLK + NM_BLK + NP_BLK, 384, 0, stream>>>(
      pc, mean, Jr, vt, sd, betas, rot, trans, org, anch,
      Upart, Wp, cmpart, JJpart, Mcpart, X, sapart);
  k_red2<<<129, 384, 0, stream>>>(Upart, JJpart, Mcpart, cmpart, betas, X,
                                  Wp, JJ, Mc, gWS, out);
  k_finish<<<64, 384, 0, stream>>>(betas, org, JJ, Mc, sapart, gWS, Wp, out);
}